// Round 4
// baseline (218.773 us; speedup 1.0000x reference)
//
#include <hip/hip_runtime.h>
#include <hip/hip_bf16.h>
#include <cstdint>
#include <cstddef>

// Problem constants (fixed by setup_inputs)
#define N_ROWS 2048
#define DIM    512
#define QN     3
#define KQ     8192
#define NCOL   (QN * KQ)   // 24576
#define NCLASS 16

#define BM 128
#define BN 128
#define BK 128             // fp8: 128 cols = 128 B per row slab
#define NBLK (NCOL / BN)   // 192 column blocks

typedef __attribute__((ext_vector_type(4))) float f32x4;
typedef __attribute__((ext_vector_type(8))) int   i32x8;

// ---------------------------------------------------------------------------
// Kernel 1: L2-normalize rows of x and q_data, scale by 16, cast to fp8
// e4m3 (OCP). One wave per row; 4 rows per 256-thread block.
// Scale 16: unit-norm 512-d rows have elem sigma ~0.044 -> x16 clears
// e4m3's 2^-6 subnormal cliff. GEMM result = 256*sim.
// GLOBAL HALF-SWAP: rows with bit3 set store each 16-B chunk's two 8-B
// halves swapped (bakes the LDS XOR swizzle's half-bit into global memory
// so global_load_lds still works; GEMM b64 LDS reads hit all 32 banks).
// ROUND-9: also zeroes T[2048] (row-total accumulator for the fused
// atomic epilogue) and out[0] (replaces hipMemsetAsync).
// ---------------------------------------------------------------------------
__global__ __launch_bounds__(256) void norm_cast_kernel(
    const float* __restrict__ x, const float* __restrict__ q,
    unsigned char* __restrict__ xb, unsigned char* __restrict__ qb,
    float* __restrict__ T, float* __restrict__ out) {
    if (blockIdx.x == 0 && threadIdx.x == 0) out[0] = 0.f;
    if (blockIdx.x < 8) T[blockIdx.x * 256 + threadIdx.x] = 0.f;
    int row = blockIdx.x * 4 + (threadIdx.x >> 6);
    int lane = threadIdx.x & 63;
    const float* src;
    unsigned char* dst;
    if (row < N_ROWS) {
        src = x + (size_t)row * DIM;
        dst = xb + (size_t)row * DIM;
    } else {
        src = q + (size_t)(row - N_ROWS) * DIM;
        dst = qb + (size_t)(row - N_ROWS) * DIM;
    }
    float4 v0 = ((const float4*)src)[lane * 2];
    float4 v1 = ((const float4*)src)[lane * 2 + 1];
    float ss = v0.x*v0.x + v0.y*v0.y + v0.z*v0.z + v0.w*v0.w
             + v1.x*v1.x + v1.y*v1.y + v1.z*v1.z + v1.w*v1.w;
    #pragma unroll
    for (int off = 1; off < 64; off <<= 1)
        ss += __shfl_xor(ss, off, 64);
    float inv = 16.0f / fmaxf(sqrtf(ss), 1e-12f);
    // HW fp8 pack: v_cvt_pk_fp8_f32 (src0 -> low byte, src1 -> high byte)
    int w0 = __builtin_amdgcn_cvt_pk_fp8_f32(v0.x * inv, v0.y * inv, 0,  false);
    w0     = __builtin_amdgcn_cvt_pk_fp8_f32(v0.z * inv, v0.w * inv, w0, true);
    int w1 = __builtin_amdgcn_cvt_pk_fp8_f32(v1.x * inv, v1.y * inv, 0,  false);
    w1     = __builtin_amdgcn_cvt_pk_fp8_f32(v1.z * inv, v1.w * inv, w1, true);
    uint2 o; o.x = (unsigned)w0; o.y = (unsigned)w1;
    // half-swap bake: lane's 8 B go to (lane*8) ^ (row.bit3 * 8)
    int r3 = (row >> 3) & 1;
    *(uint2*)(dst + ((lane * 8) ^ (r3 << 3))) = o;
}

// ---------------------------------------------------------------------------
// Kernel 2: fp8 MFMA GEMM (M=2048, N=24576, K=512), result = 256*sim.
// MX-scaled mfma_scale_f32_16x16x128_f8f6f4, unit scales (e8m0=127 -> 2^0).
// ROUND-9 (post-mortems 6-8): MX needs >= round-0 residency to pay, since
// the 2-barrier structure's critical path is stage+vmcnt+barrier, hidden
// only by other resident blocks.
//   - 256-thread blocks, acc[4][4] (round-0 residency shape; LDS allows
//     5 blocks/CU, VGPR target <=128 -> 4 blocks/CU).
//   - Register discipline WITHOUT launch_bounds forcing (round-7 spill
//     lesson): A-fragments in two mt-halves (a0,a1 = 16 VGPRs resident),
//     bb streamed (8 VGPRs); B re-read once per half.  sched_barrier(0)
//     between halves stops the scheduler from hoisting both halves'
//     fragments (round-6's 144-VGPR failure).  Live ~90.
//   - Fused atomic epilogue: no P matrix, no LDS reduce, no 2nd barrier;
//     l15==0 lanes atomicAdd row partials into T[2048] (384 adds/address
//     across the whole kernel -- negligible contention).
// Fragment layout (f8f6f4, fp8): A row = lane&15, k-window =
// (lane>>4)*32 + 0..31 (8 VGPRs contiguous); B identical per-row.
// C/D layout == 16x16x32 fp8 (shape-determined).
// - 4-bit XOR LDS layout: element (r,k) at byte
//     r*128 + (((k>>4) ^ (r&7))<<4) + ((((k>>3)&1) ^ ((r>>3)&1))<<3) + (k&7)
//   Half-bit pre-baked into GLOBAL layout by norm_cast; staging is
//   wave-uniform base + lane*16 with pre-swizzled global source.  Each
//   quad's 16 b64 lanes cover all 32 banks exactly once -> zero conflicts
//   (measured 0 in rounds 0-3); fragment read addresses loop-invariant.
// - XCD-aware block decode (FETCH ~10.4 MB measured).
// ---------------------------------------------------------------------------
__global__ __launch_bounds__(256) void gemm_epilogue_kernel(
    const unsigned char* __restrict__ Xb,   // [2048][512] fp8 (half-swapped)
    const unsigned char* __restrict__ Qb,   // [24576][512] fp8 (half-swapped)
    const int* __restrict__ targets,
    const int* __restrict__ q_targets,
    const int* __restrict__ order_p,
    float* __restrict__ T) {                 // [N_ROWS] row totals (atomic)

    __shared__ unsigned char As[BM * BK];   // 16 KB
    __shared__ unsigned char Bs[BN * BK];   // 16 KB

    const int tid  = threadIdx.x;
    const int lane = tid & 63;
    const int wave = tid >> 6;               // 0..3
    const int wm = wave >> 1, wn = wave & 1;
    const int quad = lane >> 4;              // 0..3
    const int l15  = lane & 15;
    const int l7   = l15 & 7;                // row mod 8 for swizzle
    const int l3   = (l15 >> 3) & 1;         // row bit3 for half-swap

    // XCD-aware decode: consecutive linear IDs round-robin across 8 XCDs.
    const int b    = blockIdx.x;             // 0..3071
    const int xcd  = b & 7;
    const int g    = b >> 3;                 // 0..383
    const int colb = (g >> 4) * 8 + xcd;     // 0..191, cols == xcd (mod 8)
    const int rowb = g & 15;                 // 0..15
    const int m0 = rowb * BM;
    const int n0 = colb * BN;

    f32x4 acc[4][4];
    #pragma unroll
    for (int i = 0; i < 4; i++)
        #pragma unroll
        for (int j = 0; j < 4; j++)
            acc[i][j] = (f32x4){0.f, 0.f, 0.f, 0.f};

    // Staging: chunk = wave*4+j covers rows chunk*8..+7 (1 KB LDS block).
    // Lane l -> row chunk*8 + (l>>3), global 16B seg (l&7)^(l>>3) (inverse
    // of the read-side slot16 swizzle; the half-bit lives in global layout).
    const int stR = (lane >> 3);                       // 0..7
    const int stC = ((lane & 7) ^ stR) * 16;           // byte offset in row slab

    // Loop-invariant fragment-read offsets.  Lane's logical k-window is
    // bytes quad*32 .. +31 of the 128-B row slab:
    //   slot c (16 B): C = quad*2+c, physical slot = (C ^ l7)<<4
    //   half h (8 B):  physical = (h ^ l3)<<3
    const int sw0 = ((((quad << 1)    ) ^ l7) << 4) + (l3 << 3); // c=0, logical half0
    const int sw1 = ((((quad << 1) | 1) ^ l7) << 4) + (l3 << 3); // c=1, logical half0

    union frag { long l[4]; i32x8 v; };

    for (int k0 = 0; k0 < DIM; k0 += BK) {
        #pragma unroll
        for (int j = 0; j < 4; j++) {
            int chunk = wave * 4 + j;                 // 0..15
            int R = chunk * 8 + stR;                  // 0..127
            const unsigned char* ga = Xb + (size_t)(m0 + R) * DIM + k0 + stC;
            const unsigned char* gb = Qb + (size_t)(n0 + R) * DIM + k0 + stC;
            __builtin_amdgcn_global_load_lds(
                (const __attribute__((address_space(1))) unsigned int*)ga,
                (__attribute__((address_space(3))) unsigned int*)&As[chunk * 1024 + lane * 16],
                16, 0, 0);
            __builtin_amdgcn_global_load_lds(
                (const __attribute__((address_space(1))) unsigned int*)gb,
                (__attribute__((address_space(3))) unsigned int*)&Bs[chunk * 1024 + lane * 16],
                16, 0, 0);
        }
        __syncthreads();

        // Two mt-halves: hold 2 A-frags (16 VGPRs), stream bb (8 VGPRs).
        // sched_barrier(0) pins the halves so the allocator never holds
        // all 4 A-frags at once (round-6's 144-VGPR cliff).
        #pragma unroll
        for (int half = 0; half < 2; half++) {
            __builtin_amdgcn_sched_barrier(0);
            frag a0, a1;
            {
                const unsigned char* ba0 = &As[(wm * 64 + half * 32      + l15) * BK];
                const unsigned char* ba1 = &As[(wm * 64 + half * 32 + 16 + l15) * BK];
                a0.l[0] = *(const long*)(ba0 + sw0);
                a0.l[1] = *(const long*)(ba0 + (sw0 ^ 8));
                a0.l[2] = *(const long*)(ba0 + sw1);
                a0.l[3] = *(const long*)(ba0 + (sw1 ^ 8));
                a1.l[0] = *(const long*)(ba1 + sw0);
                a1.l[1] = *(const long*)(ba1 + (sw0 ^ 8));
                a1.l[2] = *(const long*)(ba1 + sw1);
                a1.l[3] = *(const long*)(ba1 + (sw1 ^ 8));
            }
            #pragma unroll
            for (int nt = 0; nt < 4; nt++) {
                frag bb;
                const unsigned char* bp = &Bs[(wn * 64 + nt * 16 + l15) * BK];
                bb.l[0] = *(const long*)(bp + sw0);
                bb.l[1] = *(const long*)(bp + (sw0 ^ 8));
                bb.l[2] = *(const long*)(bp + sw1);
                bb.l[3] = *(const long*)(bp + (sw1 ^ 8));
                acc[half * 2][nt] = __builtin_amdgcn_mfma_scale_f32_16x16x128_f8f6f4(
                    a0.v, bb.v, acc[half * 2][nt],
                    0 /*cbsz: fp8*/, 0 /*blgp: fp8*/,
                    0, 0x7f7f7f7f, 0, 0x7f7f7f7f);
                acc[half * 2 + 1][nt] = __builtin_amdgcn_mfma_scale_f32_16x16x128_f8f6f4(
                    a1.v, bb.v, acc[half * 2 + 1][nt],
                    0 /*cbsz: fp8*/, 0 /*blgp: fp8*/,
                    0, 0x7f7f7f7f, 0, 0x7f7f7f7f);
            }
        }
        __syncthreads();
    }

    // ---- Fused epilogue: exp + mask + quad-reduce + atomicAdd to T ----
    const int ord  = order_p[0];
    const int qIdx = colb / (KQ / BN);   // block lies entirely within one queue
    const bool isOrd = (qIdx == ord);
    const int kbase = n0 - qIdx * KQ;

    int qtv[4] = {0, 0, 0, 0};
    if (isOrd) {
        #pragma unroll
        for (int nt = 0; nt < 4; nt++)
            qtv[nt] = q_targets[ord * KQ + kbase + wn * 64 + nt * 16 + l15];
    }

    #pragma unroll
    for (int mt = 0; mt < 4; mt++) {
        int rowl = wm * 64 + mt * 16 + quad * 4;        // local row base
        int tg[4] = {0, 0, 0, 0};
        if (isOrd) {
            #pragma unroll
            for (int reg = 0; reg < 4; reg++) tg[reg] = targets[m0 + rowl + reg];
        }
        #pragma unroll
        for (int reg = 0; reg < 4; reg++) {
            float s = 0.f;
            #pragma unroll
            for (int nt = 0; nt < 4; nt++) {
                float v256 = acc[mt][nt][reg];          // 256 * sim
                // e = exp(4*sim - 4) = exp(v256/64 - 4)
                float e = __expf(v256 * 0.015625f - 4.0f);
                if (isOrd && tg[reg] == qtv[nt]) e = 0.f;  // masked entry
                s += e;
            }
            // reduce over the 16 columns held across lanes of this quad
            s += __shfl_xor(s, 1, 64);
            s += __shfl_xor(s, 2, 64);
            s += __shfl_xor(s, 4, 64);
            s += __shfl_xor(s, 8, 64);
            if (l15 == 0)
                atomicAdd(&T[m0 + rowl + reg], s);
        }
    }
}

// ---------------------------------------------------------------------------
// Kernel 3: count via per-wave ballot histogram, then accumulate
// mean(log(T[r]/cnt)) into out (zeroed by norm_cast earlier in stream).
// T[r] already holds the full masked row total (atomic accumulation in
// the gemm epilogue) -- the 192-partial P loop is gone.
// ---------------------------------------------------------------------------
__global__ __launch_bounds__(256) void reduce_kernel(
    const float* __restrict__ T,
    const int* __restrict__ targets,
    const int* __restrict__ q_targets,
    const int* __restrict__ order_p,
    float* __restrict__ out) {
    __shared__ int hist[NCLASS];
    __shared__ float partial[4];
    int tid = threadIdx.x;
    int wave = tid >> 6, lane = tid & 63;
    if (tid < NCLASS) hist[tid] = 0;
    __syncthreads();
    int ord = order_p[0];

    int local[NCLASS];
    #pragma unroll
    for (int c = 0; c < NCLASS; c++) local[c] = 0;
    for (int i = tid; i < KQ; i += 256) {           // 32 iterations
        int v = q_targets[ord * KQ + i];
        #pragma unroll
        for (int c = 0; c < NCLASS; c++)
            local[c] += __popcll(__ballot(v == c)); // wave-uniform count
    }
    if (lane == 0) {
        #pragma unroll
        for (int c = 0; c < NCLASS; c++)
            atomicAdd(&hist[c], local[c]);
    }
    __syncthreads();

    int r = blockIdx.x * 256 + tid;      // 8 blocks x 256 = 2048 rows
    float total = T[r];
    float cnt = (float)(QN * KQ - hist[targets[r]]);
    float v = logf(total / cnt);

    #pragma unroll
    for (int off = 1; off < 64; off <<= 1)
        v += __shfl_xor(v, off, 64);
    if (lane == 0) partial[wave] = v;
    __syncthreads();
    if (tid == 0)
        atomicAdd(out, (partial[0] + partial[1] + partial[2] + partial[3])
                       * (1.0f / (float)N_ROWS));
}

// ---------------------------------------------------------------------------
extern "C" void kernel_launch(void* const* d_in, const int* in_sizes, int n_in,
                              void* d_out, int out_size, void* d_ws, size_t ws_size,
                              hipStream_t stream) {
    const float* x         = (const float*)d_in[0];
    const float* q         = (const float*)d_in[1];
    const int*   targets   = (const int*)d_in[2];
    const int*   q_targets = (const int*)d_in[3];
    const int*   order     = (const int*)d_in[4];
    float* out = (float*)d_out;

    // Workspace: T (2048 f32 = 8 KB) | Xb (1 MB fp8) | Qb (12 MB fp8)
    char* ws = (char*)d_ws;
    float* T = (float*)ws;
    unsigned char* Xb = (unsigned char*)(ws + (size_t)N_ROWS * 4);
    unsigned char* Qb = Xb + (size_t)N_ROWS * DIM;

    norm_cast_kernel<<<(N_ROWS + NCOL) / 4, 256, 0, stream>>>(x, q, Xb, Qb, T, out);

    gemm_epilogue_kernel<<<NBLK * (N_ROWS / BM), 256, 0, stream>>>(
        Xb, Qb, targets, q_targets, order, T);

    reduce_kernel<<<N_ROWS / 256, 256, 0, stream>>>(T, targets, q_targets, order, out);
}

// Round 5
// 167.722 us; speedup vs baseline: 1.3044x; 1.3044x over previous
//
#include <hip/hip_runtime.h>
#include <hip/hip_bf16.h>
#include <cstdint>
#include <cstddef>

// Problem constants (fixed by setup_inputs)
#define N_ROWS 2048
#define DIM    512
#define QN     3
#define KQ     8192
#define NCOL   (QN * KQ)   // 24576
#define NCLASS 16

#define BM 128
#define BN 128
#define BK 128             // fp8: 128 cols = 128 B per row slab
#define NBLK (NCOL / BN)   // 192 column blocks

typedef __attribute__((ext_vector_type(4))) float f32x4;

// ---------------------------------------------------------------------------
// Kernel 1: L2-normalize rows of x and q_data, scale by 16, cast to fp8
// e4m3 (OCP). One wave per row; 4 rows per 256-thread block.
// Scale 16: unit-norm 512-d rows have elem sigma ~0.044 -> x16 clears
// e4m3's 2^-6 subnormal cliff. GEMM result = 256*sim.
// GLOBAL HALF-SWAP: rows with bit3 set store each 16-B chunk's two 8-B
// halves swapped (bakes the LDS XOR swizzle's half-bit into global memory
// so global_load_lds still works; GEMM b64 LDS reads hit all 32 banks).
// Zeroes T[2048] (row-total accumulator for the fused atomic epilogue)
// and out[0] (replaces the hipMemsetAsync dispatch).
// ---------------------------------------------------------------------------
__global__ __launch_bounds__(256) void norm_cast_kernel(
    const float* __restrict__ x, const float* __restrict__ q,
    unsigned char* __restrict__ xb, unsigned char* __restrict__ qb,
    float* __restrict__ T, float* __restrict__ out) {
    if (blockIdx.x == 0 && threadIdx.x == 0) out[0] = 0.f;
    if (blockIdx.x < 8) T[blockIdx.x * 256 + threadIdx.x] = 0.f;
    int row = blockIdx.x * 4 + (threadIdx.x >> 6);
    int lane = threadIdx.x & 63;
    const float* src;
    unsigned char* dst;
    if (row < N_ROWS) {
        src = x + (size_t)row * DIM;
        dst = xb + (size_t)row * DIM;
    } else {
        src = q + (size_t)(row - N_ROWS) * DIM;
        dst = qb + (size_t)(row - N_ROWS) * DIM;
    }
    float4 v0 = ((const float4*)src)[lane * 2];
    float4 v1 = ((const float4*)src)[lane * 2 + 1];
    float ss = v0.x*v0.x + v0.y*v0.y + v0.z*v0.z + v0.w*v0.w
             + v1.x*v1.x + v1.y*v1.y + v1.z*v1.z + v1.w*v1.w;
    #pragma unroll
    for (int off = 1; off < 64; off <<= 1)
        ss += __shfl_xor(ss, off, 64);
    float inv = 16.0f / fmaxf(sqrtf(ss), 1e-12f);
    // HW fp8 pack: v_cvt_pk_fp8_f32 (src0 -> low byte, src1 -> high byte)
    int w0 = __builtin_amdgcn_cvt_pk_fp8_f32(v0.x * inv, v0.y * inv, 0,  false);
    w0     = __builtin_amdgcn_cvt_pk_fp8_f32(v0.z * inv, v0.w * inv, w0, true);
    int w1 = __builtin_amdgcn_cvt_pk_fp8_f32(v1.x * inv, v1.y * inv, 0,  false);
    w1     = __builtin_amdgcn_cvt_pk_fp8_f32(v1.z * inv, v1.w * inv, w1, true);
    uint2 o; o.x = (unsigned)w0; o.y = (unsigned)w1;
    // half-swap bake: lane's 8 B go to (lane*8) ^ (row.bit3 * 8)
    int r3 = (row >> 3) & 1;
    *(uint2*)(dst + ((lane * 8) ^ (r3 << 3))) = o;
}

// ---------------------------------------------------------------------------
// Kernel 2: fp8 MFMA GEMM (M=2048, N=24576, K=512), result = 256*sim.
// ROUND-10 (post-mortems 6-9): MX K=128 is DEAD in this 2-barrier
// structure -- its 16-VGPR operand pairs + 64-VGPR acc can't be held
// under the 128-VGPR occupancy cliff by this compiler (144 VGPR round 6,
// spill round 7, 104-but-2-blocks round 8, 200 VGPR round 9).  Reverted
// to the verified round-5 inner loop: non-scaled 16x16x32 fp8 MFMA,
// 72 VGPR, 4+ blocks/CU, 56.7-57.1 us measured, MfmaUtil ~35%, zero
// LDS bank conflicts = the ~900 TF ceiling of this structure.
// KEPT from round 9 (verified correct, ~free): fused atomic epilogue --
// no P matrix, no LDS reduce; l15==0 lanes atomicAdd row partials into
// T[2048] (384 adds/address over ~50 us -- negligible contention;
// WRITE_SIZE 1.5 -> 12 MB measured, ~2 us).
// - BK=128 (4 K-iters, 8 barriers).
// - 4-bit XOR LDS layout: element (r,k) at byte
//     r*128 + (((k>>4) ^ (r&7))<<4) + ((((k>>3)&1) ^ ((r>>3)&1))<<3) + (k&7)
//   Half-bit pre-baked into GLOBAL layout by norm_cast; staging is
//   wave-uniform base + lane*16 with pre-swizzled global source.  Each
//   quad's 16 b64 lanes cover all 32 banks exactly once -> zero conflicts.
// - XCD-aware block decode (FETCH ~10.4 MB measured).
// ---------------------------------------------------------------------------
__global__ __launch_bounds__(256) void gemm_epilogue_kernel(
    const unsigned char* __restrict__ Xb,   // [2048][512] fp8 (half-swapped)
    const unsigned char* __restrict__ Qb,   // [24576][512] fp8 (half-swapped)
    const int* __restrict__ targets,
    const int* __restrict__ q_targets,
    const int* __restrict__ order_p,
    float* __restrict__ T) {                 // [N_ROWS] row totals (atomic)

    __shared__ unsigned char As[BM * BK];   // 16 KB
    __shared__ unsigned char Bs[BN * BK];   // 16 KB

    const int tid  = threadIdx.x;
    const int lane = tid & 63;
    const int wave = tid >> 6;               // 0..3
    const int wm = wave >> 1, wn = wave & 1;
    const int quad = lane >> 4;              // 0..3
    const int l15  = lane & 15;
    const int l7   = l15 & 7;                // row mod 8 for swizzle
    const int l3   = (l15 >> 3) & 1;         // row bit3 for half-swap

    // XCD-aware decode: consecutive linear IDs round-robin across 8 XCDs.
    const int b    = blockIdx.x;             // 0..3071
    const int xcd  = b & 7;
    const int g    = b >> 3;                 // 0..383
    const int colb = (g >> 4) * 8 + xcd;     // 0..191, cols == xcd (mod 8)
    const int rowb = g & 15;                 // 0..15
    const int m0 = rowb * BM;
    const int n0 = colb * BN;

    f32x4 acc[4][4];
    #pragma unroll
    for (int i = 0; i < 4; i++)
        #pragma unroll
        for (int j = 0; j < 4; j++)
            acc[i][j] = (f32x4){0.f, 0.f, 0.f, 0.f};

    // Staging: chunk = wave*4+j covers rows chunk*8..+7 (1 KB LDS block).
    // Lane l -> row chunk*8 + (l>>3), global 16B seg (l&7)^(l>>3) (inverse
    // of the read-side slot16 swizzle; the half-bit lives in global layout).
    const int stR = (lane >> 3);                       // 0..7
    const int stC = ((lane & 7) ^ stR) * 16;           // byte offset in row slab

    for (int k0 = 0; k0 < DIM; k0 += BK) {
        #pragma unroll
        for (int j = 0; j < 4; j++) {
            int chunk = wave * 4 + j;                 // 0..15
            int R = chunk * 8 + stR;                  // 0..127
            const unsigned char* ga = Xb + (size_t)(m0 + R) * DIM + k0 + stC;
            const unsigned char* gb = Qb + (size_t)(n0 + R) * DIM + k0 + stC;
            __builtin_amdgcn_global_load_lds(
                (const __attribute__((address_space(1))) unsigned int*)ga,
                (__attribute__((address_space(3))) unsigned int*)&As[chunk * 1024 + lane * 16],
                16, 0, 0);
            __builtin_amdgcn_global_load_lds(
                (const __attribute__((address_space(1))) unsigned int*)gb,
                (__attribute__((address_space(3))) unsigned int*)&Bs[chunk * 1024 + lane * 16],
                16, 0, 0);
        }
        __syncthreads();

        #pragma unroll
        for (int ks = 0; ks < BK; ks += 32) {
            // frag k-range = ks + quad*8 .. +8:
            //   16B col C = ks/16 + quad/2, half h = quad&1.
            // addr = row*128 + ((C ^ l7)<<4) + ((h ^ l3)<<3)
            const int sw = ((((ks >> 4) + (quad >> 1)) ^ l7) << 4)
                         + (((quad & 1) ^ l3) << 3);
            long a[4], bb[4];
            #pragma unroll
            for (int mt = 0; mt < 4; mt++)
                a[mt] = *(const long*)&As[(wm * 64 + mt * 16 + l15) * BK + sw];
            #pragma unroll
            for (int nt = 0; nt < 4; nt++)
                bb[nt] = *(const long*)&Bs[(wn * 64 + nt * 16 + l15) * BK + sw];
            #pragma unroll
            for (int mt = 0; mt < 4; mt++)
                #pragma unroll
                for (int nt = 0; nt < 4; nt++)
                    acc[mt][nt] = __builtin_amdgcn_mfma_f32_16x16x32_fp8_fp8(
                        a[mt], bb[nt], acc[mt][nt], 0, 0, 0);
        }
        __syncthreads();
    }

    // ---- Fused epilogue: exp + mask + quad-reduce + atomicAdd to T ----
    const int ord  = order_p[0];
    const int qIdx = colb / (KQ / BN);   // block lies entirely within one queue
    const bool isOrd = (qIdx == ord);
    const int kbase = n0 - qIdx * KQ;

    int qtv[4] = {0, 0, 0, 0};
    if (isOrd) {
        #pragma unroll
        for (int nt = 0; nt < 4; nt++)
            qtv[nt] = q_targets[ord * KQ + kbase + wn * 64 + nt * 16 + l15];
    }

    #pragma unroll
    for (int mt = 0; mt < 4; mt++) {
        int rowl = wm * 64 + mt * 16 + quad * 4;        // local row base
        int tg[4] = {0, 0, 0, 0};
        if (isOrd) {
            #pragma unroll
            for (int reg = 0; reg < 4; reg++) tg[reg] = targets[m0 + rowl + reg];
        }
        #pragma unroll
        for (int reg = 0; reg < 4; reg++) {
            float s = 0.f;
            #pragma unroll
            for (int nt = 0; nt < 4; nt++) {
                float v256 = acc[mt][nt][reg];          // 256 * sim
                // e = exp(4*sim - 4) = exp(v256/64 - 4)
                float e = __expf(v256 * 0.015625f - 4.0f);
                if (isOrd && tg[reg] == qtv[nt]) e = 0.f;  // masked entry
                s += e;
            }
            // reduce over the 16 columns held across lanes of this quad
            s += __shfl_xor(s, 1, 64);
            s += __shfl_xor(s, 2, 64);
            s += __shfl_xor(s, 4, 64);
            s += __shfl_xor(s, 8, 64);
            if (l15 == 0)
                atomicAdd(&T[m0 + rowl + reg], s);
        }
    }
}

// ---------------------------------------------------------------------------
// Kernel 3: count via per-wave ballot histogram, then accumulate
// mean(log(T[r]/cnt)) into out (zeroed by norm_cast earlier in stream).
// T[r] already holds the full masked row total (atomic accumulation in
// the gemm epilogue) -- the 192-partial P loop is gone.
// ---------------------------------------------------------------------------
__global__ __launch_bounds__(256) void reduce_kernel(
    const float* __restrict__ T,
    const int* __restrict__ targets,
    const int* __restrict__ q_targets,
    const int* __restrict__ order_p,
    float* __restrict__ out) {
    __shared__ int hist[NCLASS];
    __shared__ float partial[4];
    int tid = threadIdx.x;
    int wave = tid >> 6, lane = tid & 63;
    if (tid < NCLASS) hist[tid] = 0;
    __syncthreads();
    int ord = order_p[0];

    int local[NCLASS];
    #pragma unroll
    for (int c = 0; c < NCLASS; c++) local[c] = 0;
    for (int i = tid; i < KQ; i += 256) {           // 32 iterations
        int v = q_targets[ord * KQ + i];
        #pragma unroll
        for (int c = 0; c < NCLASS; c++)
            local[c] += __popcll(__ballot(v == c)); // wave-uniform count
    }
    if (lane == 0) {
        #pragma unroll
        for (int c = 0; c < NCLASS; c++)
            atomicAdd(&hist[c], local[c]);
    }
    __syncthreads();

    int r = blockIdx.x * 256 + tid;      // 8 blocks x 256 = 2048 rows
    float total = T[r];
    float cnt = (float)(QN * KQ - hist[targets[r]]);
    float v = logf(total / cnt);

    #pragma unroll
    for (int off = 1; off < 64; off <<= 1)
        v += __shfl_xor(v, off, 64);
    if (lane == 0) partial[wave] = v;
    __syncthreads();
    if (tid == 0)
        atomicAdd(out, (partial[0] + partial[1] + partial[2] + partial[3])
                       * (1.0f / (float)N_ROWS));
}

// ---------------------------------------------------------------------------
extern "C" void kernel_launch(void* const* d_in, const int* in_sizes, int n_in,
                              void* d_out, int out_size, void* d_ws, size_t ws_size,
                              hipStream_t stream) {
    const float* x         = (const float*)d_in[0];
    const float* q         = (const float*)d_in[1];
    const int*   targets   = (const int*)d_in[2];
    const int*   q_targets = (const int*)d_in[3];
    const int*   order     = (const int*)d_in[4];
    float* out = (float*)d_out;

    // Workspace: T (2048 f32 = 8 KB) | Xb (1 MB fp8) | Qb (12 MB fp8)
    char* ws = (char*)d_ws;
    float* T = (float*)ws;
    unsigned char* Xb = (unsigned char*)(ws + (size_t)N_ROWS * 4);
    unsigned char* Qb = Xb + (size_t)N_ROWS * DIM;

    norm_cast_kernel<<<(N_ROWS + NCOL) / 4, 256, 0, stream>>>(x, q, Xb, Qb, T, out);

    gemm_epilogue_kernel<<<NBLK * (N_ROWS / BM), 256, 0, stream>>>(
        Xb, Qb, targets, q_targets, order, T);

    reduce_kernel<<<N_ROWS / 256, 256, 0, stream>>>(T, targets, q_targets, order, out);
}